// Round 16
// baseline (68.586 us; speedup 1.0000x reference)
//
#include <hip/hip_runtime.h>
#include <hip/hip_bf16.h>
#include <math.h>

#define B_ 2
#define M_ 5
#define H_ 8
#define C_ 256
#define DH 32
#define NQ 790
#define NS 790
#define QT32 25    // ceil(790/32)
#define VROW 800   // per-m padded s extent in vT2
#define PPAD 800   // pp row pad

typedef __attribute__((ext_vector_type(8))) __bf16 bf16x8;
typedef __attribute__((ext_vector_type(16))) float f32x16;
typedef __attribute__((ext_vector_type(2))) unsigned int u32x2;
typedef unsigned int u32;
typedef unsigned short u16;

#define LOG2E 1.4426950408889634f

static __device__ __forceinline__ u16 bf16bits(float v) {
  union { __bf16 h; u16 u; } x; x.h = (__bf16)v; return x.u;
}
static __device__ __forceinline__ u32 pack2bf(float a, float b) {
  union { __bf16 h[2]; u32 u; } x; x.h[0] = (__bf16)a; x.h[1] = (__bf16)b; return x.u;
}
// Safe half-swap reduce via SSA intrinsic (round-10 lesson: inline asm with
// equal-valued "+v" operands can be allocated to ONE register -> self-swap).
static __device__ __forceinline__ float halfswap_sum(float ts) {
  union { float f; u32 u; } c; c.f = ts;
  u32x2 r = __builtin_amdgcn_permlane32_swap(c.u, c.u, false, false);
  union { u32 u; float f; } a, b; a.u = r[0]; b.u = r[1];
  return a.f + b.f;
}
static __device__ __forceinline__ void pswap(u32& x, u32& y) {
  u32x2 r = __builtin_amdgcn_permlane32_swap(x, y, false, false);
  x = r[0]; y = r[1];
}

// ================= wcvt_all: all four weight matrices f32 -> bf16, + vT2 pad fill =================
__global__ __launch_bounds__(256) void wcvt_all(const float* __restrict__ Wq,
    const float* __restrict__ Wk, const float* __restrict__ Wv,
    const float* __restrict__ Wo,
    u16* __restrict__ wqb, u16* __restrict__ wkb, u16* __restrict__ wvb,
    u16* __restrict__ wob, u16* __restrict__ vT2) {
  int bid = blockIdx.x;
  int tid = threadIdx.x;
  if (bid == 32) {
    int c = tid;
#pragma unroll
    for (int m = 0; m < M_; ++m) {
      u32* p = (u32*)(vT2 + (size_t)c * (M_ * VROW) + m * VROW + 790);
#pragma unroll
      for (int i = 0; i < 5; ++i) p[i] = 0;
    }
    return;
  }
  int mat = bid >> 3;
  const float* src0 = (mat == 0) ? Wq : (mat == 1) ? Wk : (mat == 2) ? Wv : Wo;
  u16* dst0 = (mat == 0) ? wqb : (mat == 1) ? wkb : (mat == 2) ? wvb : wob;
  int base = (bid & 7) * 8192;
#pragma unroll
  for (int k = 0; k < 4; ++k) {
    int idx = base + k * 2048 + tid * 8;
    const float* src = src0 + idx;
    float4 f0 = *(const float4*)src, f1 = *(const float4*)(src + 4);
    u16 v[8];
    v[0]=bf16bits(f0.x); v[1]=bf16bits(f0.y); v[2]=bf16bits(f0.z); v[3]=bf16bits(f0.w);
    v[4]=bf16bits(f1.x); v[5]=bf16bits(f1.y); v[6]=bf16bits(f1.z); v[7]=bf16bits(f1.w);
    *(uint4*)(dst0 + idx) = *(uint4*)v;
  }
}

// ================= stage1: projection GEMMs (bf16 W) + pos softmax, heavy-first =================
#define GEMM_N 149
#define POS0 149

#define PROJ_STEP(ACC, BY)                                                 \
  {                                                                        \
    int bcol_ = (BY) * 64 + wc * 32 + lo;                                  \
    bf16x8 b_ = *(const bf16x8*)(Wmb + (size_t)bcol_ * C_ + k0);           \
    ACC = __builtin_amdgcn_mfma_f32_32x32x16_bf16(a_, b_, ACC, 0, 0, 0);   \
  }

#define STORE_QK(ACC, BY)                                                  \
  {                                                                        \
    int bcol_ = (BY) * 64 + wc * 32 + lo;                                  \
    float bvv_ = bias[bcol_];                                              \
    _Pragma("unroll")                                                      \
    for (int r_ = 0; r_ < 16; ++r_) {                                      \
      int row_ = (r_ & 3) + 8 * (r_ >> 2) + 4 * hi;                        \
      int grow_ = grow0 + wr * 32 + row_;                                  \
      if (grow_ < R) {                                                     \
        float v_ = (ACC[r_] + bvv_) * scale;                               \
        int seg_ = grow_ / 790, srow_ = grow_ - seg_ * 790;                \
        size_t addr_ = ((size_t)(seg_ * H_ + (bcol_ >> 5)) * 790 + srow_) * 32 + (bcol_ & 31); \
        outp[addr_] = bf16bits(v_);                                        \
      }                                                                    \
    }                                                                      \
  }

#define STORE_V(ACC, BY)                                                   \
  {                                                                        \
    int bcol_ = (BY) * 64 + wc * 32 + lo;                                  \
    float bvv_ = bias[bcol_];                                              \
    int cIn_ = wc * 32 + lo;                                               \
    _Pragma("unroll")                                                      \
    for (int r_ = 0; r_ < 16; ++r_) {                                      \
      int row_ = (r_ & 3) + 8 * (r_ >> 2) + 4 * hi;                        \
      Tls[cIn_][wr * 32 + row_] = bf16bits(ACC[r_] + bvv_);                \
    }                                                                      \
    __syncthreads();                                                       \
    {                                                                      \
      int c_l = tid >> 2, g_l = (tid & 3) * 16;                            \
      int gcol = (BY) * 64 + c_l;                                          \
      int g0v = grow0 + g_l;                                               \
      u16 vals_[16];                                                       \
      _Pragma("unroll")                                                    \
      for (int i_ = 0; i_ < 16; ++i_) vals_[i_] = Tls[c_l][g_l + i_];      \
      int mA_ = g0v / 790, mB_ = (g0v + 15) / 790;                         \
      u16* dst_ = vT2 + (size_t)gcol * (M_ * VROW);                        \
      if (mB_ < M_ && mA_ == mB_) {                                        \
        size_t base_ = (size_t)mA_ * VROW + (g0v - mA_ * 790);             \
        *(uint4*)(dst_ + base_)     = *(uint4*)(vals_);                    \
        *(uint4*)(dst_ + base_ + 8) = *(uint4*)(vals_ + 8);                \
      } else {                                                             \
        _Pragma("unroll")                                                  \
        for (int i_ = 0; i_ < 16; ++i_) {                                  \
          int g_ = g0v + i_;                                               \
          if (g_ < M_ * 790) {                                             \
            int mm_ = g_ / 790, ss_ = g_ - mm_ * 790;                      \
            dst_[(size_t)mm_ * VROW + ss_] = vals_[i_];                    \
          }                                                                \
        }                                                                  \
      }                                                                    \
    }                                                                      \
    __syncthreads();                                                       \
  }

__global__ __launch_bounds__(256) void stage1(const float* __restrict__ qf,
    const float* __restrict__ sf, const float* __restrict__ rel,
    const u16* __restrict__ wqb, const float* __restrict__ bq,
    const u16* __restrict__ wkb, const float* __restrict__ bk,
    const u16* __restrict__ wvb, const float* __restrict__ bv,
    const float* __restrict__ Wp, const float* __restrict__ bp,
    u16* __restrict__ qb, u16* __restrict__ kb, u16* __restrict__ vT2,
    u16* __restrict__ pp, float qscale) {
  __shared__ u16 Tls[64][72];
  int bid = blockIdx.x;
  int tid = threadIdx.x;

  if (bid < GEMM_N) {
    int j = bid;
    const float* A; const u16* Wmb; const float* bias; int R; float scale; int role; int bx;
    if (j < 25)      { A = qf; Wmb = wqb; bias = bq; R = B_ * NQ; scale = qscale; role = 0; bx = j; }
    else if (j < 87) { A = sf; Wmb = wkb; bias = bk; R = M_ * NS; scale = 1.f;    role = 1; bx = j - 25; }
    else             { A = sf; Wmb = wvb; bias = bv; R = M_ * NS; scale = 1.f;    role = 2; bx = j - 87; }

    int wave = tid >> 6, lane = tid & 63;
    int lo = lane & 31, hi = lane >> 5;
    int wr = wave >> 1, wc = wave & 1;
    int grow0 = bx * 64;
    int arow = grow0 + wr * 32 + lo;
    int ar = arow < R ? arow : R - 1;

    f32x16 acc0, acc1, acc2, acc3;
#pragma unroll
    for (int r = 0; r < 16; ++r) { acc0[r] = 0.f; acc1[r] = 0.f; acc2[r] = 0.f; acc3[r] = 0.f; }
#pragma unroll
    for (int kk = 0; kk < 16; ++kk) {
      int k0 = kk * 16 + hi * 8;
      const float* af = A + (size_t)ar * C_ + k0;
      float4 f0 = *(const float4*)af, f1 = *(const float4*)(af + 4);
      bf16x8 a_;
      a_[0]=(__bf16)f0.x; a_[1]=(__bf16)f0.y; a_[2]=(__bf16)f0.z; a_[3]=(__bf16)f0.w;
      a_[4]=(__bf16)f1.x; a_[5]=(__bf16)f1.y; a_[6]=(__bf16)f1.z; a_[7]=(__bf16)f1.w;
      PROJ_STEP(acc0, 0);
      PROJ_STEP(acc1, 1);
      PROJ_STEP(acc2, 2);
      PROJ_STEP(acc3, 3);
    }

    if (role < 2) {
      u16* outp = (role == 0) ? qb : kb;
      STORE_QK(acc0, 0);
      STORE_QK(acc1, 1);
      STORE_QK(acc2, 2);
      STORE_QK(acc3, 3);
    } else {
      STORE_V(acc0, 0);
      STORE_V(acc1, 1);
      STORE_V(acc2, 2);
      STORE_V(acc3, 3);
    }
    return;
  }

  // ---- positional softmax: block = 2 q, wave = (q, 4 heads), 2 s per lane ----
  {
    int pj = bid - POS0;
    int wave = tid >> 6, lane = tid & 63;
    int q = pj * 2 + (wave >> 1);
    int h0 = (wave & 1) * 4;
    float rd0[7], rx0[7], ry0[7], rd1[7], rx1[7], ry1[7];
#pragma unroll
    for (int t = 0; t < 7; ++t) {
      int s0 = 2 * lane + 128 * t;
      int s1 = s0 + 1;
      if (s0 < NS) {
        const float* rp = rel + ((size_t)q * NS + s0) * 3;
        rd0[t] = rp[0]; rx0[t] = rp[1]; ry0[t] = rp[2];
        if (s1 < NS) { rd1[t] = rp[3]; rx1[t] = rp[4]; ry1[t] = rp[5]; }
        else         { rd1[t] = 0.f; rx1[t] = 0.f; ry1[t] = 0.f; }
      } else {
        rd0[t] = 0.f; rx0[t] = 0.f; ry0[t] = 0.f;
        rd1[t] = 0.f; rx1[t] = 0.f; ry1[t] = 0.f;
      }
    }
    for (int h = h0; h < h0 + 4; ++h) {
      float w0 = Wp[h * 3] * LOG2E, w1 = Wp[h * 3 + 1] * LOG2E,
            w2 = Wp[h * 3 + 2] * LOG2E, b = bp[h] * LOG2E;
      float e0[7], e1[7], sm = 0.f;
#pragma unroll
      for (int t = 0; t < 7; ++t) {
        int s0 = 2 * lane + 128 * t;
        float v0 = rd0[t] * w0 + rx0[t] * w1 + ry0[t] * w2 + b;
        float v1 = rd1[t] * w0 + rx1[t] * w1 + ry1[t] * w2 + b;
        e0[t] = (s0 < NS)     ? exp2f(v0) : 0.f;
        e1[t] = (s0 + 1 < NS) ? exp2f(v1) : 0.f;
        sm += e0[t] + e1[t];
      }
#pragma unroll
      for (int off = 32; off; off >>= 1) sm += __shfl_xor(sm, off);
      float inv = 1.f / sm;
      u16* row = pp + ((size_t)h * NQ + q) * PPAD;
#pragma unroll
      for (int t = 0; t < 7; ++t) {
        int s0 = 2 * lane + 128 * t;
        if (s0 < PPAD)
          *(u32*)(row + s0) = pack2bf(e0[t] * inv, e1[t] * inv);
      }
    }
  }
}

// ================= fused attention (latency-ordered body + setprio + 1-barrier merge) =================
static __device__ __forceinline__ void wave_range(int wave, int& st, int& en) {
  st = wave * 6 + (wave ? 1 : 0);
  en = st + (wave ? 6 : 7);
}

#define SM_PV(c_, OACC, ZR, FV0, FV1)                                      \
  {                                                                        \
    float p_[16];                                                          \
    _Pragma("unroll")                                                      \
    for (int r_ = 0; r_ < 16; ++r_) p_[r_] = exp2f(c_[r_]);                \
    float s0_ = p_[0]+p_[1],  s1_ = p_[2]+p_[3];                           \
    float s2_ = p_[4]+p_[5],  s3_ = p_[6]+p_[7];                           \
    float s4_ = p_[8]+p_[9],  s5_ = p_[10]+p_[11];                         \
    float s6_ = p_[12]+p_[13], s7_ = p_[14]+p_[15];                        \
    s0_ += s1_; s2_ += s3_; s4_ += s5_; s6_ += s7_;                        \
    s0_ += s2_; s4_ += s6_;                                                \
    ZR += halfswap_sum(s0_ + s4_);                                         \
    u32 pk_[8];                                                            \
    _Pragma("unroll")                                                      \
    for (int t_ = 0; t_ < 8; ++t_) pk_[t_] = pack2bf(p_[2*t_], p_[2*t_+1]); \
    pswap(pk_[0], pk_[2]);                                                 \
    pswap(pk_[1], pk_[3]);                                                 \
    pswap(pk_[4], pk_[6]);                                                 \
    pswap(pk_[5], pk_[7]);                                                 \
    union { u32 u[4]; bf16x8 v; } pa_, pb_;                                \
    pa_.u[0] = pk_[0]; pa_.u[1] = pk_[1]; pa_.u[2] = pk_[2]; pa_.u[3] = pk_[3]; \
    pb_.u[0] = pk_[4]; pb_.u[1] = pk_[5]; pb_.u[2] = pk_[6]; pb_.u[3] = pk_[7]; \
    __builtin_amdgcn_s_setprio(1);                                         \
    OACC = __builtin_amdgcn_mfma_f32_32x32x16_bf16(FV0, pa_.v, OACC, 0, 0, 0); \
    OACC = __builtin_amdgcn_mfma_f32_32x32x16_bf16(FV1, pb_.v, OACC, 0, 0, 0); \
    __builtin_amdgcn_s_setprio(0);                                         \
  }

#define TILE_BODY(KC0,KC1, KN0,KN1, IT, NT)                                \
  {                                                                        \
    bf16x8 vf0 = *(const bf16x8*)(vbase + (IT) * 32 + hi8);                \
    bf16x8 vf1 = *(const bf16x8*)(vbase + (IT) * 32 + 16 + hi8);           \
    bf16x8 pf0 = *(const bf16x8*)(pbase + (IT) * 32 + hi8);                \
    bf16x8 pf1 = *(const bf16x8*)(pbase + (IT) * 32 + 16 + hi8);           \
    int srn_ = (NT) * 32 + lo; if (srn_ >= NS) srn_ = NS - 1;              \
    KN0 = *(const bf16x8*)(kbase + (size_t)srn_ * 32 + hi8);               \
    KN1 = *(const bf16x8*)(kbase + (size_t)srn_ * 32 + 16 + hi8);          \
    f32x16 c0_, c1_;                                                       \
    _Pragma("unroll")                                                      \
    for (int r_ = 0; r_ < 16; ++r_) { c0_[r_] = 0.f; c1_[r_] = 0.f; }      \
    __builtin_amdgcn_s_setprio(1);                                         \
    c0_ = __builtin_amdgcn_mfma_f32_32x32x16_bf16(KC0, fq00, c0_, 0, 0, 0);\
    c0_ = __builtin_amdgcn_mfma_f32_32x32x16_bf16(KC1, fq01, c0_, 0, 0, 0);\
    c1_ = __builtin_amdgcn_mfma_f32_32x32x16_bf16(KC0, fq10, c1_, 0, 0, 0);\
    c1_ = __builtin_amdgcn_mfma_f32_32x32x16_bf16(KC1, fq11, c1_, 0, 0, 0);\
    __builtin_amdgcn_s_setprio(0);                                         \
    if ((IT) == 24) {                                                      \
      _Pragma("unroll")                                                    \
      for (int r_ = 0; r_ < 16; ++r_) {                                    \
        int sl_ = (r_ & 3) + 8 * (r_ >> 2) + 4 * hi;                       \
        if (768 + sl_ >= NS) { c0_[r_] = -1e30f; c1_[r_] = -1e30f; }       \
      }                                                                    \
    }                                                                      \
    SM_PV(c0_, O0, Z0, vf0, vf1);                                          \
    __builtin_amdgcn_s_setprio(1);                                         \
    Opos = __builtin_amdgcn_mfma_f32_32x32x16_bf16(vf0, pf0, Opos, 0, 0, 0);\
    Opos = __builtin_amdgcn_mfma_f32_32x32x16_bf16(vf1, pf1, Opos, 0, 0, 0);\
    __builtin_amdgcn_s_setprio(0);                                         \
    SM_PV(c1_, O1, Z1, vf0, vf1);                                          \
  }

__global__ __launch_bounds__(256, 3) void attn2(const u16* __restrict__ qb,
    const u16* __restrict__ kb, const u16* __restrict__ vT2,
    const u16* __restrict__ pp, const float* __restrict__ gating,
    u16* __restrict__ opb) {
  int logical = (blockIdx.x & 7) * 125 + (blockIdx.x >> 3);
  int m  = logical % M_;
  int r2 = logical / M_;
  int qt = r2 % QT32;
  int h  = r2 / QT32;
  int tid = threadIdx.x;
  int wave = tid >> 6, lane = tid & 63;
  int lo = lane & 31, hi = lane >> 5, hi8 = hi * 8;
  int qg = qt * 32 + lo;
  int qc = qg < NQ ? qg : NQ - 1;

  const u16* qp0 = qb + ((size_t)(0 * H_ + h) * NQ + qc) * 32 + hi8;
  const u16* qp1 = qb + ((size_t)(1 * H_ + h) * NQ + qc) * 32 + hi8;
  bf16x8 fq00 = *(const bf16x8*)qp0;
  bf16x8 fq01 = *(const bf16x8*)(qp0 + 16);
  bf16x8 fq10 = *(const bf16x8*)qp1;
  bf16x8 fq11 = *(const bf16x8*)(qp1 + 16);
  const u16* kbase = kb + ((size_t)(m * H_ + h) * NS) * 32;
  const u16* vbase = vT2 + (size_t)(h * DH + lo) * (M_ * VROW) + m * VROW;
  const u16* pbase = pp + ((size_t)h * NQ + qc) * PPAD;

  f32x16 O0, O1, Opos;
#pragma unroll
  for (int r = 0; r < 16; ++r) { O0[r] = 0.f; O1[r] = 0.f; Opos[r] = 0.f; }
  float Z0 = 0.f, Z1 = 0.f;
  int st, en; wave_range(wave, st, en);

  bf16x8 ak0, ak1, bk0, bk1;
  {
    int sr0 = st * 32 + lo; if (sr0 >= NS) sr0 = NS - 1;
    ak0 = *(const bf16x8*)(kbase + (size_t)sr0 * 32 + hi8);
    ak1 = *(const bf16x8*)(kbase + (size_t)sr0 * 32 + 16 + hi8);
  }
  int it = st;
  while (it + 2 <= en) {
    TILE_BODY(ak0, ak1, bk0, bk1, it, it + 1);
    int nt2 = (it + 2 < en) ? it + 2 : it + 1;
    TILE_BODY(bk0, bk1, ak0, ak1, it + 1, nt2);
    it += 2;
  }
  if (it < en) TILE_BODY(ak0, ak1, bk0, bk1, it, it);

  // ---- split-s merge: single barrier, disjoint LDS for O0/O1/Opos ----
  __shared__ float Os[3][4][32][33];   // 50688 B
  __shared__ float Zs[2][4][32];       //  1024 B
#pragma unroll
  for (int r = 0; r < 16; ++r) {
    int dd = (r & 3) + 8 * (r >> 2) + 4 * hi;
    Os[0][wave][dd][lo] = O0[r];
    Os[1][wave][dd][lo] = O1[r];
    Os[2][wave][dd][lo] = Opos[r];
  }
  if (hi == 0) { Zs[0][wave][lo] = Z0; Zs[1][wave][lo] = Z1; }
  __syncthreads();

  float g = 1.f / (1.f + __expf(-gating[h]));
  int d = tid & 31, qi = tid >> 5;
  u16* out0 = opb + ((size_t)(0 * M_ + m) * NQ) * C_ + h * DH + d;
  u16* out1 = opb + ((size_t)(1 * M_ + m) * NQ) * C_ + h * DH + d;
#pragma unroll
  for (int k = 0; k < 4; ++k) {
    int ql = qi + 8 * k;
    int qgl = qt * 32 + ql;
    if (qgl < NQ) {
      float zg0 = Zs[0][0][ql] + Zs[0][1][ql] + Zs[0][2][ql] + Zs[0][3][ql];
      float zg1 = Zs[1][0][ql] + Zs[1][1][ql] + Zs[1][2][ql] + Zs[1][3][ql];
      float oc0 = Os[0][0][d][ql] + Os[0][1][d][ql] + Os[0][2][d][ql] + Os[0][3][d][ql];
      float oc1 = Os[1][0][d][ql] + Os[1][1][d][ql] + Os[1][2][d][ql] + Os[1][3][d][ql];
      float op  = Os[2][0][d][ql] + Os[2][1][d][ql] + Os[2][2][d][ql] + Os[2][3][d][ql];
      out0[(size_t)qgl * C_] = bf16bits((1.f - g) * oc0 / zg0 + g * op);
      out1[(size_t)qgl * C_] = bf16bits((1.f - g) * oc1 / zg1 + g * op);
    }
  }
}

// ================= final output GEMM (bf16 A, bf16 W, f32 out, 2 col-tiles) =================
__global__ __launch_bounds__(256) void out_gemm(const u16* __restrict__ Ap,
    const u16* __restrict__ Wb, const float* __restrict__ bias,
    float* __restrict__ outp, int R) {
  int tid = threadIdx.x;
  int wave = tid >> 6, lane = tid & 63;
  int lo = lane & 31, hi = lane >> 5;
  int wr = wave >> 1, wc = wave & 1;
  int arow = blockIdx.x * 64 + wr * 32 + lo;
  int ar = arow < R ? arow : R - 1;
  int bcolA = blockIdx.y * 128 + wc * 32 + lo;
  int bcolB = bcolA + 64;
  f32x16 accA, accB;
#pragma unroll
  for (int r = 0; r < 16; ++r) { accA[r] = 0.f; accB[r] = 0.f; }
#pragma unroll
  for (int kk = 0; kk < 16; ++kk) {
    int k0 = kk * 16 + hi * 8;
    bf16x8 a = *(const bf16x8*)(Ap + (size_t)ar * C_ + k0);
    bf16x8 bA = *(const bf16x8*)(Wb + (size_t)bcolA * C_ + k0);
    bf16x8 bB = *(const bf16x8*)(Wb + (size_t)bcolB * C_ + k0);
    accA = __builtin_amdgcn_mfma_f32_32x32x16_bf16(a, bA, accA, 0, 0, 0);
    accB = __builtin_amdgcn_mfma_f32_32x32x16_bf16(a, bB, accB, 0, 0, 0);
  }
  float bvA = bias[bcolA], bvB = bias[bcolB];
#pragma unroll
  for (int r = 0; r < 16; ++r) {
    int row = (r & 3) + 8 * (r >> 2) + 4 * hi;
    int grow = blockIdx.x * 64 + wr * 32 + row;
    if (grow < R) {
      outp[(size_t)grow * C_ + bcolA] = accA[r] + bvA;
      outp[(size_t)grow * C_ + bcolB] = accB[r] + bvB;
    }
  }
}

extern "C" void kernel_launch(void* const* d_in, const int* in_sizes, int n_in,
                              void* d_out, int out_size, void* d_ws, size_t ws_size,
                              hipStream_t stream) {
  const float* q_feat = (const float*)d_in[0];
  const float* s_feat = (const float*)d_in[1];
  const float* rel    = (const float*)d_in[2];
  const float* Wq = (const float*)d_in[3];
  const float* bq = (const float*)d_in[4];
  const float* Wk = (const float*)d_in[5];
  const float* bk = (const float*)d_in[6];
  const float* Wv = (const float*)d_in[7];
  const float* bv = (const float*)d_in[8];
  const float* Wp = (const float*)d_in[9];
  const float* bp = (const float*)d_in[10];
  const float* Wo = (const float*)d_in[11];
  const float* bo = (const float*)d_in[12];
  const float* gating = (const float*)d_in[13];
  float* out = (float*)d_out;

  char* w = (char*)d_ws;
  u16* qb  = (u16*)w;                         // B*H*NQ*32 bf16 =   808,960 B
  u16* kb  = (u16*)(w + 808960);              // M*H*NS*32      = 2,022,400
  u16* vT2 = (u16*)(w + 2831360);             // C*M*VROW       = 2,048,000
  u16* pp  = (u16*)(w + 4879360);             // H*NQ*PPAD      = 10,112,000
  u16* opb = (u16*)(w + 14991360);            // B*M*NQ*C bf16  = 4,044,800
  u16* wob = (u16*)(w + 19036160);            // C*C bf16       =   131,072
  u16* wqb = (u16*)(w + 19167232);            // C*C bf16       =   131,072
  u16* wkb = (u16*)(w + 19298304);            // C*C bf16       =   131,072
  u16* wvb = (u16*)(w + 19429376);            // C*C bf16       =   131,072

  const float QSCALE = 0.17677669529663687f * 1.4426950408889634f; // 1/sqrt(32)*log2e

  wcvt_all<<<33, 256, 0, stream>>>(Wq, Wk, Wv, Wo, wqb, wkb, wvb, wob, vT2);
  stage1<<<544, 256, 0, stream>>>(q_feat, s_feat, rel, wqb, bq, wkb, bk, wvb, bv,
                                  Wp, bp, qb, kb, vT2, pp, QSCALE);
  attn2<<<1000, 256, 0, stream>>>(qb, kb, vT2, pp, gating, opb);
  out_gemm<<<dim3(124, 2), 256, 0, stream>>>(opb, wob, bo, out, B_ * M_ * NQ);
}

// Round 17
// 66.163 us; speedup vs baseline: 1.0366x; 1.0366x over previous
//
#include <hip/hip_runtime.h>
#include <hip/hip_bf16.h>
#include <math.h>

#define B_ 2
#define M_ 5
#define H_ 8
#define C_ 256
#define DH 32
#define NQ 790
#define NS 790
#define QT32 25    // ceil(790/32)
#define VROW 800   // per-m padded s extent in vT2
#define PPAD 800   // pp row pad

typedef __attribute__((ext_vector_type(8))) __bf16 bf16x8;
typedef __attribute__((ext_vector_type(16))) float f32x16;
typedef __attribute__((ext_vector_type(2))) unsigned int u32x2;
typedef unsigned int u32;
typedef unsigned short u16;

#define LOG2E 1.4426950408889634f

static __device__ __forceinline__ u16 bf16bits(float v) {
  union { __bf16 h; u16 u; } x; x.h = (__bf16)v; return x.u;
}
static __device__ __forceinline__ u32 pack2bf(float a, float b) {
  union { __bf16 h[2]; u32 u; } x; x.h[0] = (__bf16)a; x.h[1] = (__bf16)b; return x.u;
}
// Safe half-swap reduce via SSA intrinsic (round-10 lesson: inline asm with
// equal-valued "+v" operands can be allocated to ONE register -> self-swap).
static __device__ __forceinline__ float halfswap_sum(float ts) {
  union { float f; u32 u; } c; c.f = ts;
  u32x2 r = __builtin_amdgcn_permlane32_swap(c.u, c.u, false, false);
  union { u32 u; float f; } a, b; a.u = r[0]; b.u = r[1];
  return a.f + b.f;
}
static __device__ __forceinline__ void pswap(u32& x, u32& y) {
  u32x2 r = __builtin_amdgcn_permlane32_swap(x, y, false, false);
  x = r[0]; y = r[1];
}

// ================= wcvt_all: all four weight matrices f32 -> bf16, + vT2 pad fill =================
__global__ __launch_bounds__(256) void wcvt_all(const float* __restrict__ Wq,
    const float* __restrict__ Wk, const float* __restrict__ Wv,
    const float* __restrict__ Wo,
    u16* __restrict__ wqb, u16* __restrict__ wkb, u16* __restrict__ wvb,
    u16* __restrict__ wob, u16* __restrict__ vT2) {
  int bid = blockIdx.x;
  int tid = threadIdx.x;
  if (bid == 32) {
    int c = tid;
#pragma unroll
    for (int m = 0; m < M_; ++m) {
      u32* p = (u32*)(vT2 + (size_t)c * (M_ * VROW) + m * VROW + 790);
#pragma unroll
      for (int i = 0; i < 5; ++i) p[i] = 0;
    }
    return;
  }
  int mat = bid >> 3;
  const float* src0 = (mat == 0) ? Wq : (mat == 1) ? Wk : (mat == 2) ? Wv : Wo;
  u16* dst0 = (mat == 0) ? wqb : (mat == 1) ? wkb : (mat == 2) ? wvb : wob;
  int base = (bid & 7) * 8192;
#pragma unroll
  for (int k = 0; k < 4; ++k) {
    int idx = base + k * 2048 + tid * 8;
    const float* src = src0 + idx;
    float4 f0 = *(const float4*)src, f1 = *(const float4*)(src + 4);
    u16 v[8];
    v[0]=bf16bits(f0.x); v[1]=bf16bits(f0.y); v[2]=bf16bits(f0.z); v[3]=bf16bits(f0.w);
    v[4]=bf16bits(f1.x); v[5]=bf16bits(f1.y); v[6]=bf16bits(f1.z); v[7]=bf16bits(f1.w);
    *(uint4*)(dst0 + idx) = *(uint4*)v;
  }
}

// ================= stage1: fine-grained projection GEMMs (1 col-tile/block) + pos softmax =================
// role decode over 1D grid (991 blocks):
//   [0,100)    q proj  (25 row-blocks x 4 col-tiles)
//   [100,348)  k proj  (62 x 4)
//   [348,596)  v proj + transpose (62 x 4)
//   [596,991)  pos_softmax (2 q per block, wave = (q, 4 heads))
#define QP_N 100
#define KP_N 348
#define GEMM_N 596
#define POS0 596

__global__ __launch_bounds__(256) void stage1(const float* __restrict__ qf,
    const float* __restrict__ sf, const float* __restrict__ rel,
    const u16* __restrict__ wqb, const float* __restrict__ bq,
    const u16* __restrict__ wkb, const float* __restrict__ bk,
    const u16* __restrict__ wvb, const float* __restrict__ bv,
    const float* __restrict__ Wp, const float* __restrict__ bp,
    u16* __restrict__ qb, u16* __restrict__ kb, u16* __restrict__ vT2,
    u16* __restrict__ pp, float qscale) {
  __shared__ u16 Tls[64][72];
  int bid = blockIdx.x;
  int tid = threadIdx.x;

  if (bid < GEMM_N) {
    // ---- one 64x64 output tile per block ----
    const float* A; const u16* Wmb; const float* bias; int R; float scale; int role; int j;
    if (bid < QP_N)      { A = qf; Wmb = wqb; bias = bq; R = B_ * NQ; scale = qscale; role = 0; j = bid; }
    else if (bid < KP_N) { A = sf; Wmb = wkb; bias = bk; R = M_ * NS; scale = 1.f;    role = 1; j = bid - QP_N; }
    else                 { A = sf; Wmb = wvb; bias = bv; R = M_ * NS; scale = 1.f;    role = 2; j = bid - KP_N; }
    int bx = j >> 2, by = j & 3;

    int wave = tid >> 6, lane = tid & 63;
    int lo = lane & 31, hi = lane >> 5;
    int wr = wave >> 1, wc = wave & 1;
    int grow0 = bx * 64;
    int arow = grow0 + wr * 32 + lo;
    int ar = arow < R ? arow : R - 1;
    int bcol = by * 64 + wc * 32 + lo;

    f32x16 acc;
#pragma unroll
    for (int r = 0; r < 16; ++r) acc[r] = 0.f;
#pragma unroll
    for (int kk = 0; kk < 16; ++kk) {
      int k0 = kk * 16 + hi * 8;
      const float* af = A + (size_t)ar * C_ + k0;
      float4 f0 = *(const float4*)af, f1 = *(const float4*)(af + 4);
      bf16x8 a_;
      a_[0]=(__bf16)f0.x; a_[1]=(__bf16)f0.y; a_[2]=(__bf16)f0.z; a_[3]=(__bf16)f0.w;
      a_[4]=(__bf16)f1.x; a_[5]=(__bf16)f1.y; a_[6]=(__bf16)f1.z; a_[7]=(__bf16)f1.w;
      bf16x8 b_ = *(const bf16x8*)(Wmb + (size_t)bcol * C_ + k0);
      acc = __builtin_amdgcn_mfma_f32_32x32x16_bf16(a_, b_, acc, 0, 0, 0);
    }

    float bvv = bias[bcol];
    if (role < 2) {
      u16* outp = (role == 0) ? qb : kb;
#pragma unroll
      for (int r = 0; r < 16; ++r) {
        int row = (r & 3) + 8 * (r >> 2) + 4 * hi;
        int grow = grow0 + wr * 32 + row;
        if (grow < R) {
          float v = (acc[r] + bvv) * scale;
          int seg = grow / 790, srow = grow - seg * 790;
          size_t addr = ((size_t)(seg * H_ + (bcol >> 5)) * 790 + srow) * 32 + (bcol & 31);
          outp[addr] = bf16bits(v);
        }
      }
    } else {
      // V: transpose through LDS -> vT2[c][m][800]
      int cIn = wc * 32 + lo;
#pragma unroll
      for (int r = 0; r < 16; ++r) {
        int row = (r & 3) + 8 * (r >> 2) + 4 * hi;
        Tls[cIn][wr * 32 + row] = bf16bits(acc[r] + bvv);
      }
      __syncthreads();
      int c_l = tid >> 2, g_l = (tid & 3) * 16;
      int gcol = by * 64 + c_l;
      int g0v = grow0 + g_l;
      u16 vals[16];
#pragma unroll
      for (int i = 0; i < 16; ++i) vals[i] = Tls[c_l][g_l + i];
      int mA = g0v / 790, mB = (g0v + 15) / 790;
      u16* dst = vT2 + (size_t)gcol * (M_ * VROW);
      if (mB < M_ && mA == mB) {
        size_t base = (size_t)mA * VROW + (g0v - mA * 790);
        *(uint4*)(dst + base)     = *(uint4*)(vals);
        *(uint4*)(dst + base + 8) = *(uint4*)(vals + 8);
      } else {
#pragma unroll
        for (int i = 0; i < 16; ++i) {
          int g = g0v + i;
          if (g < M_ * 790) {
            int mm = g / 790, ss = g - mm * 790;
            dst[(size_t)mm * VROW + ss] = vals[i];
          }
        }
      }
    }
    return;
  }

  // ---- positional softmax: block = 2 q, wave = (q, 4 heads), 2 s per lane ----
  {
    int pj = bid - POS0;
    int wave = tid >> 6, lane = tid & 63;
    int q = pj * 2 + (wave >> 1);
    int h0 = (wave & 1) * 4;
    float rd0[7], rx0[7], ry0[7], rd1[7], rx1[7], ry1[7];
#pragma unroll
    for (int t = 0; t < 7; ++t) {
      int s0 = 2 * lane + 128 * t;
      int s1 = s0 + 1;
      if (s0 < NS) {
        const float* rp = rel + ((size_t)q * NS + s0) * 3;
        rd0[t] = rp[0]; rx0[t] = rp[1]; ry0[t] = rp[2];
        if (s1 < NS) { rd1[t] = rp[3]; rx1[t] = rp[4]; ry1[t] = rp[5]; }
        else         { rd1[t] = 0.f; rx1[t] = 0.f; ry1[t] = 0.f; }
      } else {
        rd0[t] = 0.f; rx0[t] = 0.f; ry0[t] = 0.f;
        rd1[t] = 0.f; rx1[t] = 0.f; ry1[t] = 0.f;
      }
    }
    for (int h = h0; h < h0 + 4; ++h) {
      float w0 = Wp[h * 3] * LOG2E, w1 = Wp[h * 3 + 1] * LOG2E,
            w2 = Wp[h * 3 + 2] * LOG2E, b = bp[h] * LOG2E;
      float e0[7], e1[7], sm = 0.f;
#pragma unroll
      for (int t = 0; t < 7; ++t) {
        int s0 = 2 * lane + 128 * t;
        float v0 = rd0[t] * w0 + rx0[t] * w1 + ry0[t] * w2 + b;
        float v1 = rd1[t] * w0 + rx1[t] * w1 + ry1[t] * w2 + b;
        e0[t] = (s0 < NS)     ? exp2f(v0) : 0.f;
        e1[t] = (s0 + 1 < NS) ? exp2f(v1) : 0.f;
        sm += e0[t] + e1[t];
      }
#pragma unroll
      for (int off = 32; off; off >>= 1) sm += __shfl_xor(sm, off);
      float inv = 1.f / sm;
      u16* row = pp + ((size_t)h * NQ + q) * PPAD;
#pragma unroll
      for (int t = 0; t < 7; ++t) {
        int s0 = 2 * lane + 128 * t;
        if (s0 < PPAD)
          *(u32*)(row + s0) = pack2bf(e0[t] * inv, e1[t] * inv);
      }
    }
  }
}

// ================= fused attention (latency-ordered body + setprio + 1-barrier merge) =================
static __device__ __forceinline__ void wave_range(int wave, int& st, int& en) {
  st = wave * 6 + (wave ? 1 : 0);
  en = st + (wave ? 6 : 7);
}

#define SM_PV(c_, OACC, ZR, FV0, FV1)                                      \
  {                                                                        \
    float p_[16];                                                          \
    _Pragma("unroll")                                                      \
    for (int r_ = 0; r_ < 16; ++r_) p_[r_] = exp2f(c_[r_]);                \
    float s0_ = p_[0]+p_[1],  s1_ = p_[2]+p_[3];                           \
    float s2_ = p_[4]+p_[5],  s3_ = p_[6]+p_[7];                           \
    float s4_ = p_[8]+p_[9],  s5_ = p_[10]+p_[11];                         \
    float s6_ = p_[12]+p_[13], s7_ = p_[14]+p_[15];                        \
    s0_ += s1_; s2_ += s3_; s4_ += s5_; s6_ += s7_;                        \
    s0_ += s2_; s4_ += s6_;                                                \
    ZR += halfswap_sum(s0_ + s4_);                                         \
    u32 pk_[8];                                                            \
    _Pragma("unroll")                                                      \
    for (int t_ = 0; t_ < 8; ++t_) pk_[t_] = pack2bf(p_[2*t_], p_[2*t_+1]); \
    pswap(pk_[0], pk_[2]);                                                 \
    pswap(pk_[1], pk_[3]);                                                 \
    pswap(pk_[4], pk_[6]);                                                 \
    pswap(pk_[5], pk_[7]);                                                 \
    union { u32 u[4]; bf16x8 v; } pa_, pb_;                                \
    pa_.u[0] = pk_[0]; pa_.u[1] = pk_[1]; pa_.u[2] = pk_[2]; pa_.u[3] = pk_[3]; \
    pb_.u[0] = pk_[4]; pb_.u[1] = pk_[5]; pb_.u[2] = pk_[6]; pb_.u[3] = pk_[7]; \
    __builtin_amdgcn_s_setprio(1);                                         \
    OACC = __builtin_amdgcn_mfma_f32_32x32x16_bf16(FV0, pa_.v, OACC, 0, 0, 0); \
    OACC = __builtin_amdgcn_mfma_f32_32x32x16_bf16(FV1, pb_.v, OACC, 0, 0, 0); \
    __builtin_amdgcn_s_setprio(0);                                         \
  }

#define TILE_BODY(KC0,KC1, KN0,KN1, IT, NT)                                \
  {                                                                        \
    bf16x8 vf0 = *(const bf16x8*)(vbase + (IT) * 32 + hi8);                \
    bf16x8 vf1 = *(const bf16x8*)(vbase + (IT) * 32 + 16 + hi8);           \
    bf16x8 pf0 = *(const bf16x8*)(pbase + (IT) * 32 + hi8);                \
    bf16x8 pf1 = *(const bf16x8*)(pbase + (IT) * 32 + 16 + hi8);           \
    int srn_ = (NT) * 32 + lo; if (srn_ >= NS) srn_ = NS - 1;              \
    KN0 = *(const bf16x8*)(kbase + (size_t)srn_ * 32 + hi8);               \
    KN1 = *(const bf16x8*)(kbase + (size_t)srn_ * 32 + 16 + hi8);          \
    f32x16 c0_, c1_;                                                       \
    _Pragma("unroll")                                                      \
    for (int r_ = 0; r_ < 16; ++r_) { c0_[r_] = 0.f; c1_[r_] = 0.f; }      \
    __builtin_amdgcn_s_setprio(1);                                         \
    c0_ = __builtin_amdgcn_mfma_f32_32x32x16_bf16(KC0, fq00, c0_, 0, 0, 0);\
    c0_ = __builtin_amdgcn_mfma_f32_32x32x16_bf16(KC1, fq01, c0_, 0, 0, 0);\
    c1_ = __builtin_amdgcn_mfma_f32_32x32x16_bf16(KC0, fq10, c1_, 0, 0, 0);\
    c1_ = __builtin_amdgcn_mfma_f32_32x32x16_bf16(KC1, fq11, c1_, 0, 0, 0);\
    __builtin_amdgcn_s_setprio(0);                                         \
    if ((IT) == 24) {                                                      \
      _Pragma("unroll")                                                    \
      for (int r_ = 0; r_ < 16; ++r_) {                                    \
        int sl_ = (r_ & 3) + 8 * (r_ >> 2) + 4 * hi;                       \
        if (768 + sl_ >= NS) { c0_[r_] = -1e30f; c1_[r_] = -1e30f; }       \
      }                                                                    \
    }                                                                      \
    SM_PV(c0_, O0, Z0, vf0, vf1);                                          \
    __builtin_amdgcn_s_setprio(1);                                         \
    Opos = __builtin_amdgcn_mfma_f32_32x32x16_bf16(vf0, pf0, Opos, 0, 0, 0);\
    Opos = __builtin_amdgcn_mfma_f32_32x32x16_bf16(vf1, pf1, Opos, 0, 0, 0);\
    __builtin_amdgcn_s_setprio(0);                                         \
    SM_PV(c1_, O1, Z1, vf0, vf1);                                          \
  }

__global__ __launch_bounds__(256, 3) void attn2(const u16* __restrict__ qb,
    const u16* __restrict__ kb, const u16* __restrict__ vT2,
    const u16* __restrict__ pp, const float* __restrict__ gating,
    u16* __restrict__ opb) {
  int logical = (blockIdx.x & 7) * 125 + (blockIdx.x >> 3);
  int m  = logical % M_;
  int r2 = logical / M_;
  int qt = r2 % QT32;
  int h  = r2 / QT32;
  int tid = threadIdx.x;
  int wave = tid >> 6, lane = tid & 63;
  int lo = lane & 31, hi = lane >> 5, hi8 = hi * 8;
  int qg = qt * 32 + lo;
  int qc = qg < NQ ? qg : NQ - 1;

  const u16* qp0 = qb + ((size_t)(0 * H_ + h) * NQ + qc) * 32 + hi8;
  const u16* qp1 = qb + ((size_t)(1 * H_ + h) * NQ + qc) * 32 + hi8;
  bf16x8 fq00 = *(const bf16x8*)qp0;
  bf16x8 fq01 = *(const bf16x8*)(qp0 + 16);
  bf16x8 fq10 = *(const bf16x8*)qp1;
  bf16x8 fq11 = *(const bf16x8*)(qp1 + 16);
  const u16* kbase = kb + ((size_t)(m * H_ + h) * NS) * 32;
  const u16* vbase = vT2 + (size_t)(h * DH + lo) * (M_ * VROW) + m * VROW;
  const u16* pbase = pp + ((size_t)h * NQ + qc) * PPAD;

  f32x16 O0, O1, Opos;
#pragma unroll
  for (int r = 0; r < 16; ++r) { O0[r] = 0.f; O1[r] = 0.f; Opos[r] = 0.f; }
  float Z0 = 0.f, Z1 = 0.f;
  int st, en; wave_range(wave, st, en);

  bf16x8 ak0, ak1, bk0, bk1;
  {
    int sr0 = st * 32 + lo; if (sr0 >= NS) sr0 = NS - 1;
    ak0 = *(const bf16x8*)(kbase + (size_t)sr0 * 32 + hi8);
    ak1 = *(const bf16x8*)(kbase + (size_t)sr0 * 32 + 16 + hi8);
  }
  int it = st;
  while (it + 2 <= en) {
    TILE_BODY(ak0, ak1, bk0, bk1, it, it + 1);
    int nt2 = (it + 2 < en) ? it + 2 : it + 1;
    TILE_BODY(bk0, bk1, ak0, ak1, it + 1, nt2);
    it += 2;
  }
  if (it < en) TILE_BODY(ak0, ak1, bk0, bk1, it, it);

  // ---- split-s merge: single barrier, disjoint LDS for O0/O1/Opos ----
  __shared__ float Os[3][4][32][33];   // 50688 B
  __shared__ float Zs[2][4][32];       //  1024 B
#pragma unroll
  for (int r = 0; r < 16; ++r) {
    int dd = (r & 3) + 8 * (r >> 2) + 4 * hi;
    Os[0][wave][dd][lo] = O0[r];
    Os[1][wave][dd][lo] = O1[r];
    Os[2][wave][dd][lo] = Opos[r];
  }
  if (hi == 0) { Zs[0][wave][lo] = Z0; Zs[1][wave][lo] = Z1; }
  __syncthreads();

  float g = 1.f / (1.f + __expf(-gating[h]));
  int d = tid & 31, qi = tid >> 5;
  u16* out0 = opb + ((size_t)(0 * M_ + m) * NQ) * C_ + h * DH + d;
  u16* out1 = opb + ((size_t)(1 * M_ + m) * NQ) * C_ + h * DH + d;
#pragma unroll
  for (int k = 0; k < 4; ++k) {
    int ql = qi + 8 * k;
    int qgl = qt * 32 + ql;
    if (qgl < NQ) {
      float zg0 = Zs[0][0][ql] + Zs[0][1][ql] + Zs[0][2][ql] + Zs[0][3][ql];
      float zg1 = Zs[1][0][ql] + Zs[1][1][ql] + Zs[1][2][ql] + Zs[1][3][ql];
      float oc0 = Os[0][0][d][ql] + Os[0][1][d][ql] + Os[0][2][d][ql] + Os[0][3][d][ql];
      float oc1 = Os[1][0][d][ql] + Os[1][1][d][ql] + Os[1][2][d][ql] + Os[1][3][d][ql];
      float op  = Os[2][0][d][ql] + Os[2][1][d][ql] + Os[2][2][d][ql] + Os[2][3][d][ql];
      out0[(size_t)qgl * C_] = bf16bits((1.f - g) * oc0 / zg0 + g * op);
      out1[(size_t)qgl * C_] = bf16bits((1.f - g) * oc1 / zg1 + g * op);
    }
  }
}

// ================= final output GEMM (bf16 A, bf16 W, f32 out, 2 col-tiles) =================
__global__ __launch_bounds__(256) void out_gemm(const u16* __restrict__ Ap,
    const u16* __restrict__ Wb, const float* __restrict__ bias,
    float* __restrict__ outp, int R) {
  int tid = threadIdx.x;
  int wave = tid >> 6, lane = tid & 63;
  int lo = lane & 31, hi = lane >> 5;
  int wr = wave >> 1, wc = wave & 1;
  int arow = blockIdx.x * 64 + wr * 32 + lo;
  int ar = arow < R ? arow : R - 1;
  int bcolA = blockIdx.y * 128 + wc * 32 + lo;
  int bcolB = bcolA + 64;
  f32x16 accA, accB;
#pragma unroll
  for (int r = 0; r < 16; ++r) { accA[r] = 0.f; accB[r] = 0.f; }
#pragma unroll
  for (int kk = 0; kk < 16; ++kk) {
    int k0 = kk * 16 + hi * 8;
    bf16x8 a = *(const bf16x8*)(Ap + (size_t)ar * C_ + k0);
    bf16x8 bA = *(const bf16x8*)(Wb + (size_t)bcolA * C_ + k0);
    bf16x8 bB = *(const bf16x8*)(Wb + (size_t)bcolB * C_ + k0);
    accA = __builtin_amdgcn_mfma_f32_32x32x16_bf16(a, bA, accA, 0, 0, 0);
    accB = __builtin_amdgcn_mfma_f32_32x32x16_bf16(a, bB, accB, 0, 0, 0);
  }
  float bvA = bias[bcolA], bvB = bias[bcolB];
#pragma unroll
  for (int r = 0; r < 16; ++r) {
    int row = (r & 3) + 8 * (r >> 2) + 4 * hi;
    int grow = blockIdx.x * 64 + wr * 32 + row;
    if (grow < R) {
      outp[(size_t)grow * C_ + bcolA] = accA[r] + bvA;
      outp[(size_t)grow * C_ + bcolB] = accB[r] + bvB;
    }
  }
}

extern "C" void kernel_launch(void* const* d_in, const int* in_sizes, int n_in,
                              void* d_out, int out_size, void* d_ws, size_t ws_size,
                              hipStream_t stream) {
  const float* q_feat = (const float*)d_in[0];
  const float* s_feat = (const float*)d_in[1];
  const float* rel    = (const float*)d_in[2];
  const float* Wq = (const float*)d_in[3];
  const float* bq = (const float*)d_in[4];
  const float* Wk = (const float*)d_in[5];
  const float* bk = (const float*)d_in[6];
  const float* Wv = (const float*)d_in[7];
  const float* bv = (const float*)d_in[8];
  const float* Wp = (const float*)d_in[9];
  const float* bp = (const float*)d_in[10];
  const float* Wo = (const float*)d_in[11];
  const float* bo = (const float*)d_in[12];
  const float* gating = (const float*)d_in[13];
  float* out = (float*)d_out;

  char* w = (char*)d_ws;
  u16* qb  = (u16*)w;                         // B*H*NQ*32 bf16 =   808,960 B
  u16* kb  = (u16*)(w + 808960);              // M*H*NS*32      = 2,022,400
  u16* vT2 = (u16*)(w + 2831360);             // C*M*VROW       = 2,048,000
  u16* pp  = (u16*)(w + 4879360);             // H*NQ*PPAD      = 10,112,000
  u16* opb = (u16*)(w + 14991360);            // B*M*NQ*C bf16  = 4,044,800
  u16* wob = (u16*)(w + 19036160);            // C*C bf16       =   131,072
  u16* wqb = (u16*)(w + 19167232);            // C*C bf16       =   131,072
  u16* wkb = (u16*)(w + 19298304);            // C*C bf16       =   131,072
  u16* wvb = (u16*)(w + 19429376);            // C*C bf16       =   131,072

  const float QSCALE = 0.17677669529663687f * 1.4426950408889634f; // 1/sqrt(32)*log2e

  wcvt_all<<<33, 256, 0, stream>>>(Wq, Wk, Wv, Wo, wqb, wkb, wvb, wob, vT2);
  stage1<<<991, 256, 0, stream>>>(q_feat, s_feat, rel, wqb, bq, wkb, bk, wvb, bv,
                                  Wp, bp, qb, kb, vT2, pp, QSCALE);
  attn2<<<1000, 256, 0, stream>>>(qb, kb, vT2, pp, gating, opb);
  out_gemm<<<dim3(124, 2), 256, 0, stream>>>(opb, wob, bo, out, B_ * M_ * NQ);
}

// Round 18
// 65.588 us; speedup vs baseline: 1.0457x; 1.0088x over previous
//
#include <hip/hip_runtime.h>
#include <hip/hip_bf16.h>
#include <math.h>

#define B_ 2
#define M_ 5
#define H_ 8
#define C_ 256
#define DH 32
#define NQ 790
#define NS 790
#define QT32 25    // ceil(790/32)
#define VROW 800   // per-m padded s extent in vT2
#define PPAD 800   // pp row pad

typedef __attribute__((ext_vector_type(8))) __bf16 bf16x8;
typedef __attribute__((ext_vector_type(16))) float f32x16;
typedef __attribute__((ext_vector_type(2))) unsigned int u32x2;
typedef unsigned int u32;
typedef unsigned short u16;

#define LOG2E 1.4426950408889634f

static __device__ __forceinline__ u16 bf16bits(float v) {
  union { __bf16 h; u16 u; } x; x.h = (__bf16)v; return x.u;
}
static __device__ __forceinline__ u32 pack2bf(float a, float b) {
  union { __bf16 h[2]; u32 u; } x; x.h[0] = (__bf16)a; x.h[1] = (__bf16)b; return x.u;
}
// Safe half-swap reduce via SSA intrinsic (round-10 lesson: inline asm with
// equal-valued "+v" operands can be allocated to ONE register -> self-swap).
static __device__ __forceinline__ float halfswap_sum(float ts) {
  union { float f; u32 u; } c; c.f = ts;
  u32x2 r = __builtin_amdgcn_permlane32_swap(c.u, c.u, false, false);
  union { u32 u; float f; } a, b; a.u = r[0]; b.u = r[1];
  return a.f + b.f;
}
static __device__ __forceinline__ void pswap(u32& x, u32& y) {
  u32x2 r = __builtin_amdgcn_permlane32_swap(x, y, false, false);
  x = r[0]; y = r[1];
}
static __device__ __forceinline__ bf16x8 cvt8(const float* p) {
  float4 f0 = *(const float4*)p, f1 = *(const float4*)(p + 4);
  bf16x8 r;
  r[0]=(__bf16)f0.x; r[1]=(__bf16)f0.y; r[2]=(__bf16)f0.z; r[3]=(__bf16)f0.w;
  r[4]=(__bf16)f1.x; r[5]=(__bf16)f1.y; r[6]=(__bf16)f1.z; r[7]=(__bf16)f1.w;
  return r;
}

// ================= stage1: projection GEMMs (inline-cvt f32 W) + Wo cvt + pad + pos softmax =================
// role decode over 1D grid (1000 blocks), heavy-first:
//   [0,100)     q proj  (25 row-blocks x 4 col-tiles)
//   [100,348)   k proj  (62 x 4)
//   [348,596)   v proj + transpose (62 x 4)
//   [596,604)   Wo f32 -> bf16 (for out_gemm)
//   [604]       vT2 pad zero-fill
//   [605,1000)  pos_softmax (2 q per block, wave = (q, 4 heads))
#define QP_N 100
#define KP_N 348
#define GEMM_N 596
#define WCVT0 596
#define PADBLK 604
#define POS0 605

__global__ __launch_bounds__(256) void stage1(const float* __restrict__ qf,
    const float* __restrict__ sf, const float* __restrict__ rel,
    const float* __restrict__ Wq, const float* __restrict__ bq,
    const float* __restrict__ Wk, const float* __restrict__ bk,
    const float* __restrict__ Wv, const float* __restrict__ bv,
    const float* __restrict__ Wp, const float* __restrict__ bp,
    const float* __restrict__ Wo,
    u16* __restrict__ qb, u16* __restrict__ kb, u16* __restrict__ vT2,
    u16* __restrict__ pp, u16* __restrict__ wob, float qscale) {
  __shared__ u16 Tls[64][72];
  int bid = blockIdx.x;
  int tid = threadIdx.x;

  if (bid < GEMM_N) {
    // ---- one 64x64 output tile per block, f32 weights with inline cvt ----
    const float* A; const float* Wm; const float* bias; int R; float scale; int role; int j;
    if (bid < QP_N)      { A = qf; Wm = Wq; bias = bq; R = B_ * NQ; scale = qscale; role = 0; j = bid; }
    else if (bid < KP_N) { A = sf; Wm = Wk; bias = bk; R = M_ * NS; scale = 1.f;    role = 1; j = bid - QP_N; }
    else                 { A = sf; Wm = Wv; bias = bv; R = M_ * NS; scale = 1.f;    role = 2; j = bid - KP_N; }
    int bx = j >> 2, by = j & 3;

    int wave = tid >> 6, lane = tid & 63;
    int lo = lane & 31, hi = lane >> 5;
    int wr = wave >> 1, wc = wave & 1;
    int grow0 = bx * 64;
    int arow = grow0 + wr * 32 + lo;
    int ar = arow < R ? arow : R - 1;
    int bcol = by * 64 + wc * 32 + lo;

    f32x16 acc;
#pragma unroll
    for (int r = 0; r < 16; ++r) acc[r] = 0.f;
#pragma unroll
    for (int kk = 0; kk < 16; ++kk) {
      int k0 = kk * 16 + hi * 8;
      bf16x8 a_ = cvt8(A + (size_t)ar * C_ + k0);
      bf16x8 b_ = cvt8(Wm + (size_t)bcol * C_ + k0);
      acc = __builtin_amdgcn_mfma_f32_32x32x16_bf16(a_, b_, acc, 0, 0, 0);
    }

    float bvv = bias[bcol];
    if (role < 2) {
      u16* outp = (role == 0) ? qb : kb;
#pragma unroll
      for (int r = 0; r < 16; ++r) {
        int row = (r & 3) + 8 * (r >> 2) + 4 * hi;
        int grow = grow0 + wr * 32 + row;
        if (grow < R) {
          float v = (acc[r] + bvv) * scale;
          int seg = grow / 790, srow = grow - seg * 790;
          size_t addr = ((size_t)(seg * H_ + (bcol >> 5)) * 790 + srow) * 32 + (bcol & 31);
          outp[addr] = bf16bits(v);
        }
      }
    } else {
      // V: transpose through LDS -> vT2[c][m][800]
      int cIn = wc * 32 + lo;
#pragma unroll
      for (int r = 0; r < 16; ++r) {
        int row = (r & 3) + 8 * (r >> 2) + 4 * hi;
        Tls[cIn][wr * 32 + row] = bf16bits(acc[r] + bvv);
      }
      __syncthreads();
      int c_l = tid >> 2, g_l = (tid & 3) * 16;
      int gcol = by * 64 + c_l;
      int g0v = grow0 + g_l;
      u16 vals[16];
#pragma unroll
      for (int i = 0; i < 16; ++i) vals[i] = Tls[c_l][g_l + i];
      int mA = g0v / 790, mB = (g0v + 15) / 790;
      u16* dst = vT2 + (size_t)gcol * (M_ * VROW);
      if (mB < M_ && mA == mB) {
        size_t base = (size_t)mA * VROW + (g0v - mA * 790);
        *(uint4*)(dst + base)     = *(uint4*)(vals);
        *(uint4*)(dst + base + 8) = *(uint4*)(vals + 8);
      } else {
#pragma unroll
        for (int i = 0; i < 16; ++i) {
          int g = g0v + i;
          if (g < M_ * 790) {
            int mm = g / 790, ss = g - mm * 790;
            dst[(size_t)mm * VROW + ss] = vals[i];
          }
        }
      }
    }
    return;
  }

  if (bid < PADBLK) {
    // ---- Wo f32 -> bf16 (8 blocks x 8192 elems) ----
    int base = (bid - WCVT0) * 8192;
#pragma unroll
    for (int k = 0; k < 4; ++k) {
      int idx = base + k * 2048 + tid * 8;
      const float* src = Wo + idx;
      float4 f0 = *(const float4*)src, f1 = *(const float4*)(src + 4);
      u16 v[8];
      v[0]=bf16bits(f0.x); v[1]=bf16bits(f0.y); v[2]=bf16bits(f0.z); v[3]=bf16bits(f0.w);
      v[4]=bf16bits(f1.x); v[5]=bf16bits(f1.y); v[6]=bf16bits(f1.z); v[7]=bf16bits(f1.w);
      *(uint4*)(wob + idx) = *(uint4*)v;
    }
    return;
  }

  if (bid == PADBLK) {
    int c = tid;
#pragma unroll
    for (int m = 0; m < M_; ++m) {
      u32* p = (u32*)(vT2 + (size_t)c * (M_ * VROW) + m * VROW + 790);
#pragma unroll
      for (int i = 0; i < 5; ++i) p[i] = 0;
    }
    return;
  }

  // ---- positional softmax: block = 2 q, wave = (q, 4 heads), 2 s per lane ----
  {
    int pj = bid - POS0;
    int wave = tid >> 6, lane = tid & 63;
    int q = pj * 2 + (wave >> 1);
    int h0 = (wave & 1) * 4;
    float rd0[7], rx0[7], ry0[7], rd1[7], rx1[7], ry1[7];
#pragma unroll
    for (int t = 0; t < 7; ++t) {
      int s0 = 2 * lane + 128 * t;
      int s1 = s0 + 1;
      if (s0 < NS) {
        const float* rp = rel + ((size_t)q * NS + s0) * 3;
        rd0[t] = rp[0]; rx0[t] = rp[1]; ry0[t] = rp[2];
        if (s1 < NS) { rd1[t] = rp[3]; rx1[t] = rp[4]; ry1[t] = rp[5]; }
        else         { rd1[t] = 0.f; rx1[t] = 0.f; ry1[t] = 0.f; }
      } else {
        rd0[t] = 0.f; rx0[t] = 0.f; ry0[t] = 0.f;
        rd1[t] = 0.f; rx1[t] = 0.f; ry1[t] = 0.f;
      }
    }
    for (int h = h0; h < h0 + 4; ++h) {
      float w0 = Wp[h * 3] * LOG2E, w1 = Wp[h * 3 + 1] * LOG2E,
            w2 = Wp[h * 3 + 2] * LOG2E, b = bp[h] * LOG2E;
      float e0[7], e1[7], sm = 0.f;
#pragma unroll
      for (int t = 0; t < 7; ++t) {
        int s0 = 2 * lane + 128 * t;
        float v0 = rd0[t] * w0 + rx0[t] * w1 + ry0[t] * w2 + b;
        float v1 = rd1[t] * w0 + rx1[t] * w1 + ry1[t] * w2 + b;
        e0[t] = (s0 < NS)     ? exp2f(v0) : 0.f;
        e1[t] = (s0 + 1 < NS) ? exp2f(v1) : 0.f;
        sm += e0[t] + e1[t];
      }
#pragma unroll
      for (int off = 32; off; off >>= 1) sm += __shfl_xor(sm, off);
      float inv = 1.f / sm;
      u16* row = pp + ((size_t)h * NQ + q) * PPAD;
#pragma unroll
      for (int t = 0; t < 7; ++t) {
        int s0 = 2 * lane + 128 * t;
        if (s0 < PPAD)
          *(u32*)(row + s0) = pack2bf(e0[t] * inv, e1[t] * inv);
      }
    }
  }
}

// ================= fused attention (latency-ordered body + setprio + 1-barrier merge) =================
static __device__ __forceinline__ void wave_range(int wave, int& st, int& en) {
  st = wave * 6 + (wave ? 1 : 0);
  en = st + (wave ? 6 : 7);
}

#define SM_PV(c_, OACC, ZR, FV0, FV1)                                      \
  {                                                                        \
    float p_[16];                                                          \
    _Pragma("unroll")                                                      \
    for (int r_ = 0; r_ < 16; ++r_) p_[r_] = exp2f(c_[r_]);                \
    float s0_ = p_[0]+p_[1],  s1_ = p_[2]+p_[3];                           \
    float s2_ = p_[4]+p_[5],  s3_ = p_[6]+p_[7];                           \
    float s4_ = p_[8]+p_[9],  s5_ = p_[10]+p_[11];                         \
    float s6_ = p_[12]+p_[13], s7_ = p_[14]+p_[15];                        \
    s0_ += s1_; s2_ += s3_; s4_ += s5_; s6_ += s7_;                        \
    s0_ += s2_; s4_ += s6_;                                                \
    ZR += halfswap_sum(s0_ + s4_);                                         \
    u32 pk_[8];                                                            \
    _Pragma("unroll")                                                      \
    for (int t_ = 0; t_ < 8; ++t_) pk_[t_] = pack2bf(p_[2*t_], p_[2*t_+1]); \
    pswap(pk_[0], pk_[2]);                                                 \
    pswap(pk_[1], pk_[3]);                                                 \
    pswap(pk_[4], pk_[6]);                                                 \
    pswap(pk_[5], pk_[7]);                                                 \
    union { u32 u[4]; bf16x8 v; } pa_, pb_;                                \
    pa_.u[0] = pk_[0]; pa_.u[1] = pk_[1]; pa_.u[2] = pk_[2]; pa_.u[3] = pk_[3]; \
    pb_.u[0] = pk_[4]; pb_.u[1] = pk_[5]; pb_.u[2] = pk_[6]; pb_.u[3] = pk_[7]; \
    __builtin_amdgcn_s_setprio(1);                                         \
    OACC = __builtin_amdgcn_mfma_f32_32x32x16_bf16(FV0, pa_.v, OACC, 0, 0, 0); \
    OACC = __builtin_amdgcn_mfma_f32_32x32x16_bf16(FV1, pb_.v, OACC, 0, 0, 0); \
    __builtin_amdgcn_s_setprio(0);                                         \
  }

#define TILE_BODY(KC0,KC1, KN0,KN1, IT, NT)                                \
  {                                                                        \
    bf16x8 vf0 = *(const bf16x8*)(vbase + (IT) * 32 + hi8);                \
    bf16x8 vf1 = *(const bf16x8*)(vbase + (IT) * 32 + 16 + hi8);           \
    bf16x8 pf0 = *(const bf16x8*)(pbase + (IT) * 32 + hi8);                \
    bf16x8 pf1 = *(const bf16x8*)(pbase + (IT) * 32 + 16 + hi8);           \
    int srn_ = (NT) * 32 + lo; if (srn_ >= NS) srn_ = NS - 1;              \
    KN0 = *(const bf16x8*)(kbase + (size_t)srn_ * 32 + hi8);               \
    KN1 = *(const bf16x8*)(kbase + (size_t)srn_ * 32 + 16 + hi8);          \
    f32x16 c0_, c1_;                                                       \
    _Pragma("unroll")                                                      \
    for (int r_ = 0; r_ < 16; ++r_) { c0_[r_] = 0.f; c1_[r_] = 0.f; }      \
    __builtin_amdgcn_s_setprio(1);                                         \
    c0_ = __builtin_amdgcn_mfma_f32_32x32x16_bf16(KC0, fq00, c0_, 0, 0, 0);\
    c0_ = __builtin_amdgcn_mfma_f32_32x32x16_bf16(KC1, fq01, c0_, 0, 0, 0);\
    c1_ = __builtin_amdgcn_mfma_f32_32x32x16_bf16(KC0, fq10, c1_, 0, 0, 0);\
    c1_ = __builtin_amdgcn_mfma_f32_32x32x16_bf16(KC1, fq11, c1_, 0, 0, 0);\
    __builtin_amdgcn_s_setprio(0);                                         \
    if ((IT) == 24) {                                                      \
      _Pragma("unroll")                                                    \
      for (int r_ = 0; r_ < 16; ++r_) {                                    \
        int sl_ = (r_ & 3) + 8 * (r_ >> 2) + 4 * hi;                       \
        if (768 + sl_ >= NS) { c0_[r_] = -1e30f; c1_[r_] = -1e30f; }       \
      }                                                                    \
    }                                                                      \
    SM_PV(c0_, O0, Z0, vf0, vf1);                                          \
    __builtin_amdgcn_s_setprio(1);                                         \
    Opos = __builtin_amdgcn_mfma_f32_32x32x16_bf16(vf0, pf0, Opos, 0, 0, 0);\
    Opos = __builtin_amdgcn_mfma_f32_32x32x16_bf16(vf1, pf1, Opos, 0, 0, 0);\
    __builtin_amdgcn_s_setprio(0);                                         \
    SM_PV(c1_, O1, Z1, vf0, vf1);                                          \
  }

__global__ __launch_bounds__(256, 3) void attn2(const u16* __restrict__ qb,
    const u16* __restrict__ kb, const u16* __restrict__ vT2,
    const u16* __restrict__ pp, const float* __restrict__ gating,
    u16* __restrict__ opb) {
  int logical = (blockIdx.x & 7) * 125 + (blockIdx.x >> 3);
  int m  = logical % M_;
  int r2 = logical / M_;
  int qt = r2 % QT32;
  int h  = r2 / QT32;
  int tid = threadIdx.x;
  int wave = tid >> 6, lane = tid & 63;
  int lo = lane & 31, hi = lane >> 5, hi8 = hi * 8;
  int qg = qt * 32 + lo;
  int qc = qg < NQ ? qg : NQ - 1;

  const u16* qp0 = qb + ((size_t)(0 * H_ + h) * NQ + qc) * 32 + hi8;
  const u16* qp1 = qb + ((size_t)(1 * H_ + h) * NQ + qc) * 32 + hi8;
  bf16x8 fq00 = *(const bf16x8*)qp0;
  bf16x8 fq01 = *(const bf16x8*)(qp0 + 16);
  bf16x8 fq10 = *(const bf16x8*)qp1;
  bf16x8 fq11 = *(const bf16x8*)(qp1 + 16);
  const u16* kbase = kb + ((size_t)(m * H_ + h) * NS) * 32;
  const u16* vbase = vT2 + (size_t)(h * DH + lo) * (M_ * VROW) + m * VROW;
  const u16* pbase = pp + ((size_t)h * NQ + qc) * PPAD;

  f32x16 O0, O1, Opos;
#pragma unroll
  for (int r = 0; r < 16; ++r) { O0[r] = 0.f; O1[r] = 0.f; Opos[r] = 0.f; }
  float Z0 = 0.f, Z1 = 0.f;
  int st, en; wave_range(wave, st, en);

  bf16x8 ak0, ak1, bk0, bk1;
  {
    int sr0 = st * 32 + lo; if (sr0 >= NS) sr0 = NS - 1;
    ak0 = *(const bf16x8*)(kbase + (size_t)sr0 * 32 + hi8);
    ak1 = *(const bf16x8*)(kbase + (size_t)sr0 * 32 + 16 + hi8);
  }
  int it = st;
  while (it + 2 <= en) {
    TILE_BODY(ak0, ak1, bk0, bk1, it, it + 1);
    int nt2 = (it + 2 < en) ? it + 2 : it + 1;
    TILE_BODY(bk0, bk1, ak0, ak1, it + 1, nt2);
    it += 2;
  }
  if (it < en) TILE_BODY(ak0, ak1, bk0, bk1, it, it);

  // ---- split-s merge: single barrier, disjoint LDS for O0/O1/Opos ----
  __shared__ float Os[3][4][32][33];   // 50688 B
  __shared__ float Zs[2][4][32];       //  1024 B
#pragma unroll
  for (int r = 0; r < 16; ++r) {
    int dd = (r & 3) + 8 * (r >> 2) + 4 * hi;
    Os[0][wave][dd][lo] = O0[r];
    Os[1][wave][dd][lo] = O1[r];
    Os[2][wave][dd][lo] = Opos[r];
  }
  if (hi == 0) { Zs[0][wave][lo] = Z0; Zs[1][wave][lo] = Z1; }
  __syncthreads();

  float g = 1.f / (1.f + __expf(-gating[h]));
  int d = tid & 31, qi = tid >> 5;
  u16* out0 = opb + ((size_t)(0 * M_ + m) * NQ) * C_ + h * DH + d;
  u16* out1 = opb + ((size_t)(1 * M_ + m) * NQ) * C_ + h * DH + d;
#pragma unroll
  for (int k = 0; k < 4; ++k) {
    int ql = qi + 8 * k;
    int qgl = qt * 32 + ql;
    if (qgl < NQ) {
      float zg0 = Zs[0][0][ql] + Zs[0][1][ql] + Zs[0][2][ql] + Zs[0][3][ql];
      float zg1 = Zs[1][0][ql] + Zs[1][1][ql] + Zs[1][2][ql] + Zs[1][3][ql];
      float oc0 = Os[0][0][d][ql] + Os[0][1][d][ql] + Os[0][2][d][ql] + Os[0][3][d][ql];
      float oc1 = Os[1][0][d][ql] + Os[1][1][d][ql] + Os[1][2][d][ql] + Os[1][3][d][ql];
      float op  = Os[2][0][d][ql] + Os[2][1][d][ql] + Os[2][2][d][ql] + Os[2][3][d][ql];
      out0[(size_t)qgl * C_] = bf16bits((1.f - g) * oc0 / zg0 + g * op);
      out1[(size_t)qgl * C_] = bf16bits((1.f - g) * oc1 / zg1 + g * op);
    }
  }
}

// ================= final output GEMM (bf16 A, bf16 W, f32 out, 2 col-tiles) =================
__global__ __launch_bounds__(256) void out_gemm(const u16* __restrict__ Ap,
    const u16* __restrict__ Wb, const float* __restrict__ bias,
    float* __restrict__ outp, int R) {
  int tid = threadIdx.x;
  int wave = tid >> 6, lane = tid & 63;
  int lo = lane & 31, hi = lane >> 5;
  int wr = wave >> 1, wc = wave & 1;
  int arow = blockIdx.x * 64 + wr * 32 + lo;
  int ar = arow < R ? arow : R - 1;
  int bcolA = blockIdx.y * 128 + wc * 32 + lo;
  int bcolB = bcolA + 64;
  f32x16 accA, accB;
#pragma unroll
  for (int r = 0; r < 16; ++r) { accA[r] = 0.f; accB[r] = 0.f; }
#pragma unroll
  for (int kk = 0; kk < 16; ++kk) {
    int k0 = kk * 16 + hi * 8;
    bf16x8 a = *(const bf16x8*)(Ap + (size_t)ar * C_ + k0);
    bf16x8 bA = *(const bf16x8*)(Wb + (size_t)bcolA * C_ + k0);
    bf16x8 bB = *(const bf16x8*)(Wb + (size_t)bcolB * C_ + k0);
    accA = __builtin_amdgcn_mfma_f32_32x32x16_bf16(a, bA, accA, 0, 0, 0);
    accB = __builtin_amdgcn_mfma_f32_32x32x16_bf16(a, bB, accB, 0, 0, 0);
  }
  float bvA = bias[bcolA], bvB = bias[bcolB];
#pragma unroll
  for (int r = 0; r < 16; ++r) {
    int row = (r & 3) + 8 * (r >> 2) + 4 * hi;
    int grow = blockIdx.x * 64 + wr * 32 + row;
    if (grow < R) {
      outp[(size_t)grow * C_ + bcolA] = accA[r] + bvA;
      outp[(size_t)grow * C_ + bcolB] = accB[r] + bvB;
    }
  }
}

extern "C" void kernel_launch(void* const* d_in, const int* in_sizes, int n_in,
                              void* d_out, int out_size, void* d_ws, size_t ws_size,
                              hipStream_t stream) {
  const float* q_feat = (const float*)d_in[0];
  const float* s_feat = (const float*)d_in[1];
  const float* rel    = (const float*)d_in[2];
  const float* Wq = (const float*)d_in[3];
  const float* bq = (const float*)d_in[4];
  const float* Wk = (const float*)d_in[5];
  const float* bk = (const float*)d_in[6];
  const float* Wv = (const float*)d_in[7];
  const float* bv = (const float*)d_in[8];
  const float* Wp = (const float*)d_in[9];
  const float* bp = (const float*)d_in[10];
  const float* Wo = (const float*)d_in[11];
  const float* bo = (const float*)d_in[12];
  const float* gating = (const float*)d_in[13];
  float* out = (float*)d_out;

  char* w = (char*)d_ws;
  u16* qb  = (u16*)w;                         // B*H*NQ*32 bf16 =   808,960 B
  u16* kb  = (u16*)(w + 808960);              // M*H*NS*32      = 2,022,400
  u16* vT2 = (u16*)(w + 2831360);             // C*M*VROW       = 2,048,000
  u16* pp  = (u16*)(w + 4879360);             // H*NQ*PPAD      = 10,112,000
  u16* opb = (u16*)(w + 14991360);            // B*M*NQ*C bf16  = 4,044,800
  u16* wob = (u16*)(w + 19036160);            // C*C bf16       =   131,072

  const float QSCALE = 0.17677669529663687f * 1.4426950408889634f; // 1/sqrt(32)*log2e

  stage1<<<1000, 256, 0, stream>>>(q_feat, s_feat, rel, Wq, bq, Wk, bk, Wv, bv,
                                   Wp, bp, Wo, qb, kb, vT2, pp, wob, QSCALE);
  attn2<<<1000, 256, 0, stream>>>(qb, kb, vT2, pp, gating, opb);
  out_gemm<<<dim3(124, 2), 256, 0, stream>>>(opb, wob, bo, out, B_ * M_ * NQ);
}